// Round 1
// baseline (204.371 us; speedup 1.0000x reference)
//
#include <hip/hip_runtime.h>

// Anti-causal attention (mask: key s valid iff s > l), scale=1/8 applied to logits.
// Last query row (l = L-1) is fully masked -> softmax uniform -> out = mean(V).
// B=2, L=S=2048, H=16, E=D=64, fp32 in/out, bf16 MFMA compute.

#define B_ 2
#define L_ 2048
#define H_ 16
#define E_ 64
#define S_ 2048
#define D_ 64

typedef __attribute__((ext_vector_type(4))) float f32x4;
typedef __attribute__((ext_vector_type(8))) short short8;
typedef __attribute__((ext_vector_type(4))) unsigned int uint4v;

__device__ __forceinline__ unsigned short f2bf(float f) {
  unsigned int u = __builtin_bit_cast(unsigned int, f);
  u = (u + 0x7FFFu + ((u >> 16) & 1u)) >> 16;  // RNE
  return (unsigned short)u;
}
__device__ __forceinline__ unsigned int pkbf(float a, float b) {
  return (unsigned int)f2bf(a) | ((unsigned int)f2bf(b) << 16);
}

__global__ __launch_bounds__(256) void attn_fwd(
    const float* __restrict__ Qg, const float* __restrict__ Kg,
    const float* __restrict__ Vg, float* __restrict__ Og) {
  const int bh = blockIdx.x;
  const int b = bh >> 4, h = bh & 15;
  const int q0 = blockIdx.y << 6;            // 64 query rows per block
  const int tid = (int)threadIdx.x;
  const int lane = tid & 63;
  const int w = tid >> 6;                    // wave 0..3
  const int gp = lane >> 4;                  // 0..3
  const int c = lane & 15;                   // 0..15
  const int qbase = q0 + (w << 4);           // this wave's 16 rows

  __shared__ unsigned short Kl[32][72];      // K tile bf16, padded (144B stride)
  __shared__ unsigned short Vt[64][40];      // V tile transposed [d][s], 80B stride

  // ---- Q fragments: lane holds Q[qbase+c][8*gp + j] (e-chunks 0 and 1), pre-scaled by 1/8
  short8 qf0, qf1;
  {
    const float* qrow = Qg + ((size_t)((b * L_ + (qbase + c)) * H_ + h)) * E_;
    const f32x4* q0p = (const f32x4*)(qrow + (gp << 3));
    const f32x4* q1p = (const f32x4*)(qrow + 32 + (gp << 3));
    f32x4 a0 = q0p[0], b0 = q0p[1], a1 = q1p[0], b1 = q1p[1];
    float t0[8] = {a0[0],a0[1],a0[2],a0[3],b0[0],b0[1],b0[2],b0[3]};
    float t1[8] = {a1[0],a1[1],a1[2],a1[3],b1[0],b1[1],b1[2],b1[3]};
#pragma unroll
    for (int j = 0; j < 8; ++j) {
      qf0[j] = (short)f2bf(0.125f * t0[j]);
      qf1[j] = (short)f2bf(0.125f * t1[j]);
    }
  }

  f32x4 accO[4];
#pragma unroll
  for (int k0 = 0; k0 < 4; ++k0) accO[k0] = (f32x4){0.f, 0.f, 0.f, 0.f};
  float m_run = -1e30f, denom = 0.f;

  const int c0 = (q0 + 1) >> 5;
  const int srow = tid >> 3;                 // 0..31 (key row in tile)
  const int scol = (tid & 7) << 3;           // 0,8,...,56

  for (int ch = c0; ch < (S_ >> 5); ++ch) {
    const int s0 = ch << 5;
    __syncthreads();
    // ---- stage K (bf16) and V (bf16, transposed) from fp32 global
    {
      const size_t rbase = ((size_t)((b * S_ + (s0 + srow)) * H_ + h));
      const float* kp = Kg + rbase * E_ + scol;
      f32x4 ka = *(const f32x4*)kp;
      f32x4 kb = *(const f32x4*)(kp + 4);
      short8 kv;
      kv[0]=(short)f2bf(ka[0]); kv[1]=(short)f2bf(ka[1]);
      kv[2]=(short)f2bf(ka[2]); kv[3]=(short)f2bf(ka[3]);
      kv[4]=(short)f2bf(kb[0]); kv[5]=(short)f2bf(kb[1]);
      kv[6]=(short)f2bf(kb[2]); kv[7]=(short)f2bf(kb[3]);
      *(short8*)&Kl[srow][scol] = kv;
      const float* vp = Vg + rbase * D_ + scol;
      f32x4 va = *(const f32x4*)vp;
      f32x4 vb = *(const f32x4*)(vp + 4);
      Vt[scol + 0][srow] = f2bf(va[0]);
      Vt[scol + 1][srow] = f2bf(va[1]);
      Vt[scol + 2][srow] = f2bf(va[2]);
      Vt[scol + 3][srow] = f2bf(va[3]);
      Vt[scol + 4][srow] = f2bf(vb[0]);
      Vt[scol + 5][srow] = f2bf(vb[1]);
      Vt[scol + 6][srow] = f2bf(vb[2]);
      Vt[scol + 7][srow] = f2bf(vb[3]);
    }
    __syncthreads();
    if (s0 + 31 <= qbase) continue;          // chunk fully masked for this wave

    // ---- S^T = K_tile . Q^T  (swapped: no transpose needed for either operand)
    f32x4 st0 = {0.f,0.f,0.f,0.f}, st1 = {0.f,0.f,0.f,0.f};
    {
      short8 kf;
      kf = *(const short8*)&Kl[c][(gp << 3)];
      st0 = __builtin_amdgcn_mfma_f32_16x16x32_bf16(kf, qf0, st0, 0, 0, 0);
      kf = *(const short8*)&Kl[c][32 + (gp << 3)];
      st0 = __builtin_amdgcn_mfma_f32_16x16x32_bf16(kf, qf1, st0, 0, 0, 0);
      kf = *(const short8*)&Kl[16 + c][(gp << 3)];
      st1 = __builtin_amdgcn_mfma_f32_16x16x32_bf16(kf, qf0, st1, 0, 0, 0);
      kf = *(const short8*)&Kl[16 + c][32 + (gp << 3)];
      st1 = __builtin_amdgcn_mfma_f32_16x16x32_bf16(kf, qf1, st1, 0, 0, 0);
    }

    // ---- mask + online softmax (lane (gp,c): keys s0+16t+4gp+r of q-row qbase+c)
    const int lrow = qbase + c;
    float p[8];
    {
      float sarr[8] = {st0[0], st0[1], st0[2], st0[3], st1[0], st1[1], st1[2], st1[3]};
      float mx = -1e30f;
#pragma unroll
      for (int i = 0; i < 8; ++i) {
        int sg = s0 + ((i >> 2) << 4) + (gp << 2) + (i & 3);
        float v = (sg > lrow) ? sarr[i] : -1e30f;
        p[i] = v;
        mx = fmaxf(mx, v);
      }
      mx = fmaxf(mx, __shfl_xor(mx, 16));
      mx = fmaxf(mx, __shfl_xor(mx, 32));
      float m_new = fmaxf(m_run, mx);
      float sum = 0.f;
#pragma unroll
      for (int i = 0; i < 8; ++i) { p[i] = __expf(p[i] - m_new); sum += p[i]; }
      sum += __shfl_xor(sum, 16);
      sum += __shfl_xor(sum, 32);
      float alpha = __expf(m_run - m_new);
      m_run = m_new;
      denom = denom * alpha + sum;
      float ar0 = __shfl(alpha, (gp << 2) + 0);
      float ar1 = __shfl(alpha, (gp << 2) + 1);
      float ar2 = __shfl(alpha, (gp << 2) + 2);
      float ar3 = __shfl(alpha, (gp << 2) + 3);
#pragma unroll
      for (int k0 = 0; k0 < 4; ++k0) {
        accO[k0][0] *= ar0; accO[k0][1] *= ar1;
        accO[k0][2] *= ar2; accO[k0][3] *= ar3;
      }
    }

    // ---- build P fragment (A-operand of PV): lane needs P[row c][keys 8gp..8gp+7]
    {
      unsigned int pA0 = pkbf(p[0], p[1]), pA1 = pkbf(p[2], p[3]);
      unsigned int pB0 = pkbf(p[4], p[5]), pB1 = pkbf(p[6], p[7]);
      const int al = (gp << 1) & 3;          // 0,2,0,2
      const int src0 = (al << 4) + c, src1 = src0 + 16;
      unsigned int a0 = (unsigned int)__shfl((int)pA0, src0);
      unsigned int a1 = (unsigned int)__shfl((int)pA1, src0);
      unsigned int a2 = (unsigned int)__shfl((int)pA0, src1);
      unsigned int a3 = (unsigned int)__shfl((int)pA1, src1);
      unsigned int b0 = (unsigned int)__shfl((int)pB0, src0);
      unsigned int b1 = (unsigned int)__shfl((int)pB1, src0);
      unsigned int b2 = (unsigned int)__shfl((int)pB0, src1);
      unsigned int b3 = (unsigned int)__shfl((int)pB1, src1);
      const bool useA = (gp < 2);
      uint4v fv;
      fv[0] = useA ? a0 : b0;
      fv[1] = useA ? a1 : b1;
      fv[2] = useA ? a2 : b2;
      fv[3] = useA ? a3 : b3;
      short8 pf = __builtin_bit_cast(short8, fv);
      // ---- PV: out[16 rows][16 dims] += P(16x32) . V(32x16)
#pragma unroll
      for (int k0 = 0; k0 < 4; ++k0) {
        short8 vf = *(const short8*)&Vt[(k0 << 4) + c][(gp << 3)];
        accO[k0] = __builtin_amdgcn_mfma_f32_16x16x32_bf16(pf, vf, accO[k0], 0, 0, 0);
      }
    }
  }

  // ---- epilogue: out[row 4gp+r][16k0+c] = acc / denom(row)
  float dr[4];
  dr[0] = __shfl(denom, (gp << 2) + 0);
  dr[1] = __shfl(denom, (gp << 2) + 1);
  dr[2] = __shfl(denom, (gp << 2) + 2);
  dr[3] = __shfl(denom, (gp << 2) + 3);
#pragma unroll
  for (int r = 0; r < 4; ++r) {
    const size_t base =
        ((size_t)((b * L_ + (qbase + (gp << 2) + r)) * H_ + h)) * D_ + c;
    const float inv = 1.0f / dr[r];
    Og[base +  0] = accO[0][r] * inv;
    Og[base + 16] = accO[1][r] * inv;
    Og[base + 32] = accO[2][r] * inv;
    Og[base + 48] = accO[3][r] * inv;
  }
}

// Row L-1 is fully masked: softmax over 2048 equal logits -> uniform -> mean(V).
__global__ __launch_bounds__(256) void vmean_fix(const float* __restrict__ Vg,
                                                 float* __restrict__ Og) {
  const int bh = blockIdx.x;
  const int b = bh >> 4, h = bh & 15;
  const int t = (int)threadIdx.x;
  const int lane = t & 63, w = t >> 6;
  float sum = 0.f;
  for (int s = w; s < S_; s += 4)
    sum += Vg[((size_t)((b * S_ + s) * H_ + h)) * D_ + lane];
  __shared__ float red[4][64];
  red[w][lane] = sum;
  __syncthreads();
  if (w == 0) {
    float tot = red[0][lane] + red[1][lane] + red[2][lane] + red[3][lane];
    Og[((size_t)((b * L_ + (L_ - 1)) * H_ + h)) * D_ + lane] = tot * (1.0f / (float)S_);
  }
}

extern "C" void kernel_launch(void* const* d_in, const int* in_sizes, int n_in,
                              void* d_out, int out_size, void* d_ws, size_t ws_size,
                              hipStream_t stream) {
  const float* Q = (const float*)d_in[0];
  const float* K = (const float*)d_in[1];
  const float* V = (const float*)d_in[2];
  float* O = (float*)d_out;
  dim3 grid(B_ * H_, L_ / 64);   // x = (b,h), y = q-tile (heavy tiles dispatch first)
  attn_fwd<<<grid, dim3(256), 0, stream>>>(Q, K, V, O);
  vmean_fix<<<dim3(B_ * H_), dim3(256), 0, stream>>>(V, O);
}

// Round 2
// 107.619 us; speedup vs baseline: 1.8990x; 1.8990x over previous
//
#include <hip/hip_runtime.h>

// Anti-causal attention (mask: key s valid iff s > l), scale=1/8 applied to logits.
// Last query row (l = L-1) is fully masked -> softmax uniform -> out = mean(V).
// B=2, L=S=2048, H=16, E=D=64, fp32 in/out, bf16 MFMA compute.

#define B_ 2
#define L_ 2048
#define H_ 16
#define E_ 64
#define S_ 2048
#define D_ 64

typedef __attribute__((ext_vector_type(4))) float f32x4;
typedef __attribute__((ext_vector_type(8))) short short8;
typedef __attribute__((ext_vector_type(4))) unsigned int uint4v;

__device__ __forceinline__ unsigned short f2bf(float f) {
  unsigned int u = __builtin_bit_cast(unsigned int, f);
  u = (u + 0x7FFFu + ((u >> 16) & 1u)) >> 16;  // RNE
  return (unsigned short)u;
}
__device__ __forceinline__ unsigned int pkbf(float a, float b) {
  return (unsigned int)f2bf(a) | ((unsigned int)f2bf(b) << 16);
}

__global__ __launch_bounds__(256) void attn_fwd(
    const float* __restrict__ Qg, const float* __restrict__ Kg,
    const float* __restrict__ Vg, float* __restrict__ Og) {
  const int bh = blockIdx.x;
  const int b = bh >> 4, h = bh & 15;
  const int q0 = blockIdx.y << 6;            // 64 query rows per block
  const int tid = (int)threadIdx.x;
  const int lane = tid & 63;
  const int w = tid >> 6;                    // wave 0..3
  const int gp = lane >> 4;                  // 0..3
  const int c = lane & 15;                   // 0..15
  const int qbase = q0 + (w << 4);           // this wave's 16 rows

  __shared__ unsigned short Kl[32][72];      // K tile bf16, padded (144B stride)
  __shared__ unsigned short Vt[64][40];      // V tile transposed [d][s], 80B stride

  // ---- Q fragments: lane holds Q[qbase+c][8*gp + j] (e-chunks 0 and 1), pre-scaled by 1/8
  short8 qf0, qf1;
  {
    const float* qrow = Qg + ((size_t)((b * L_ + (qbase + c)) * H_ + h)) * E_;
    const f32x4* q0p = (const f32x4*)(qrow + (gp << 3));
    const f32x4* q1p = (const f32x4*)(qrow + 32 + (gp << 3));
    f32x4 a0 = q0p[0], b0 = q0p[1], a1 = q1p[0], b1 = q1p[1];
    float t0[8] = {a0[0],a0[1],a0[2],a0[3],b0[0],b0[1],b0[2],b0[3]};
    float t1[8] = {a1[0],a1[1],a1[2],a1[3],b1[0],b1[1],b1[2],b1[3]};
#pragma unroll
    for (int j = 0; j < 8; ++j) {
      qf0[j] = (short)f2bf(0.125f * t0[j]);
      qf1[j] = (short)f2bf(0.125f * t1[j]);
    }
  }

  f32x4 accO[4];
#pragma unroll
  for (int k0 = 0; k0 < 4; ++k0) accO[k0] = (f32x4){0.f, 0.f, 0.f, 0.f};
  float m_run = -1e30f, denom = 0.f;

  const int c0 = (q0 + 1) >> 5;
  const int srow = tid >> 3;                 // 0..31 (key row in tile)
  const int scol = (tid & 7) << 3;           // 0,8,...,56

  for (int ch = c0; ch < (S_ >> 5); ++ch) {
    const int s0 = ch << 5;
    __syncthreads();
    // ---- stage K (bf16) and V (bf16, transposed) from fp32 global
    {
      const size_t rbase = ((size_t)((b * S_ + (s0 + srow)) * H_ + h));
      const float* kp = Kg + rbase * E_ + scol;
      f32x4 ka = *(const f32x4*)kp;
      f32x4 kb = *(const f32x4*)(kp + 4);
      short8 kv;
      kv[0]=(short)f2bf(ka[0]); kv[1]=(short)f2bf(ka[1]);
      kv[2]=(short)f2bf(ka[2]); kv[3]=(short)f2bf(ka[3]);
      kv[4]=(short)f2bf(kb[0]); kv[5]=(short)f2bf(kb[1]);
      kv[6]=(short)f2bf(kb[2]); kv[7]=(short)f2bf(kb[3]);
      *(short8*)&Kl[srow][scol] = kv;
      const float* vp = Vg + rbase * D_ + scol;
      f32x4 va = *(const f32x4*)vp;
      f32x4 vb = *(const f32x4*)(vp + 4);
      Vt[scol + 0][srow] = f2bf(va[0]);
      Vt[scol + 1][srow] = f2bf(va[1]);
      Vt[scol + 2][srow] = f2bf(va[2]);
      Vt[scol + 3][srow] = f2bf(va[3]);
      Vt[scol + 4][srow] = f2bf(vb[0]);
      Vt[scol + 5][srow] = f2bf(vb[1]);
      Vt[scol + 6][srow] = f2bf(vb[2]);
      Vt[scol + 7][srow] = f2bf(vb[3]);
    }
    __syncthreads();
    if (s0 + 31 <= qbase) continue;          // chunk fully masked for this wave

    // ---- S^T = K_tile . Q^T  (swapped: no transpose needed for either operand)
    f32x4 st0 = {0.f,0.f,0.f,0.f}, st1 = {0.f,0.f,0.f,0.f};
    {
      short8 kf;
      kf = *(const short8*)&Kl[c][(gp << 3)];
      st0 = __builtin_amdgcn_mfma_f32_16x16x32_bf16(kf, qf0, st0, 0, 0, 0);
      kf = *(const short8*)&Kl[c][32 + (gp << 3)];
      st0 = __builtin_amdgcn_mfma_f32_16x16x32_bf16(kf, qf1, st0, 0, 0, 0);
      kf = *(const short8*)&Kl[16 + c][(gp << 3)];
      st1 = __builtin_amdgcn_mfma_f32_16x16x32_bf16(kf, qf0, st1, 0, 0, 0);
      kf = *(const short8*)&Kl[16 + c][32 + (gp << 3)];
      st1 = __builtin_amdgcn_mfma_f32_16x16x32_bf16(kf, qf1, st1, 0, 0, 0);
    }

    // ---- mask + online softmax (lane (gp,c): keys s0+16t+4gp+r of q-row qbase+c)
    const int lrow = qbase + c;
    float p[8];
    {
      float sarr[8] = {st0[0], st0[1], st0[2], st0[3], st1[0], st1[1], st1[2], st1[3]};
      float mx = -1e30f;
#pragma unroll
      for (int i = 0; i < 8; ++i) {
        int sg = s0 + ((i >> 2) << 4) + (gp << 2) + (i & 3);
        float v = (sg > lrow) ? sarr[i] : -1e30f;
        p[i] = v;
        mx = fmaxf(mx, v);
      }
      mx = fmaxf(mx, __shfl_xor(mx, 16));
      mx = fmaxf(mx, __shfl_xor(mx, 32));
      float m_new = fmaxf(m_run, mx);
      float sum = 0.f;
#pragma unroll
      for (int i = 0; i < 8; ++i) { p[i] = __expf(p[i] - m_new); sum += p[i]; }
      sum += __shfl_xor(sum, 16);
      sum += __shfl_xor(sum, 32);
      float alpha = __expf(m_run - m_new);
      m_run = m_new;
      denom = denom * alpha + sum;
      float ar0 = __shfl(alpha, (gp << 2) + 0);
      float ar1 = __shfl(alpha, (gp << 2) + 1);
      float ar2 = __shfl(alpha, (gp << 2) + 2);
      float ar3 = __shfl(alpha, (gp << 2) + 3);
#pragma unroll
      for (int k0 = 0; k0 < 4; ++k0) {
        accO[k0][0] *= ar0; accO[k0][1] *= ar1;
        accO[k0][2] *= ar2; accO[k0][3] *= ar3;
      }
    }

    // ---- build P fragment (A-operand of PV): lane needs P[row c][keys 8gp..8gp+7]
    {
      unsigned int pA0 = pkbf(p[0], p[1]), pA1 = pkbf(p[2], p[3]);
      unsigned int pB0 = pkbf(p[4], p[5]), pB1 = pkbf(p[6], p[7]);
      const int al = (gp << 1) & 3;          // 0,2,0,2
      const int src0 = (al << 4) + c, src1 = src0 + 16;
      unsigned int a0 = (unsigned int)__shfl((int)pA0, src0);
      unsigned int a1 = (unsigned int)__shfl((int)pA1, src0);
      unsigned int a2 = (unsigned int)__shfl((int)pA0, src1);
      unsigned int a3 = (unsigned int)__shfl((int)pA1, src1);
      unsigned int b0 = (unsigned int)__shfl((int)pB0, src0);
      unsigned int b1 = (unsigned int)__shfl((int)pB1, src0);
      unsigned int b2 = (unsigned int)__shfl((int)pB0, src1);
      unsigned int b3 = (unsigned int)__shfl((int)pB1, src1);
      const bool useA = (gp < 2);
      uint4v fv;
      fv[0] = useA ? a0 : b0;
      fv[1] = useA ? a1 : b1;
      fv[2] = useA ? a2 : b2;
      fv[3] = useA ? a3 : b3;
      short8 pf = __builtin_bit_cast(short8, fv);
      // ---- PV: out[16 rows][16 dims] += P(16x32) . V(32x16)
#pragma unroll
      for (int k0 = 0; k0 < 4; ++k0) {
        short8 vf = *(const short8*)&Vt[(k0 << 4) + c][(gp << 3)];
        accO[k0] = __builtin_amdgcn_mfma_f32_16x16x32_bf16(pf, vf, accO[k0], 0, 0, 0);
      }
    }
  }

  // ---- epilogue: out[row 4gp+r][16k0+c] = acc / denom(row)
  float dr[4];
  dr[0] = __shfl(denom, (gp << 2) + 0);
  dr[1] = __shfl(denom, (gp << 2) + 1);
  dr[2] = __shfl(denom, (gp << 2) + 2);
  dr[3] = __shfl(denom, (gp << 2) + 3);
#pragma unroll
  for (int r = 0; r < 4; ++r) {
    const int grow = qbase + (gp << 2) + r;
    if (grow == L_ - 1) continue;            // fully-masked row: vmean kernels own it
    const size_t base = ((size_t)((b * L_ + grow) * H_ + h)) * D_ + c;
    const float inv = 1.0f / dr[r];
    Og[base +  0] = accO[0][r] * inv;
    Og[base + 16] = accO[1][r] * inv;
    Og[base + 32] = accO[2][r] * inv;
    Og[base + 48] = accO[3][r] * inv;
  }
}

// ---- Row L-1 fixup, stage 1: 512 blocks, each sums a 128-row slab of V for one (b,h).
__global__ __launch_bounds__(256) void vmean_part(const float* __restrict__ Vg,
                                                  float* __restrict__ ws) {
  const int g = blockIdx.x;                  // g = bh*16 + slab
  const int slab = g & 15, bh = g >> 4;
  const int b = bh >> 4, h = bh & 15;
  const int lane = (int)threadIdx.x & 63, w = (int)threadIdx.x >> 6;
  const int s0 = (slab << 7) + (w << 5);     // 32 rows per wave
  const float* base = Vg + ((size_t)((b * S_ + s0) * H_ + h)) * D_ + lane;
  float sum = 0.f;
#pragma unroll 4
  for (int i = 0; i < 32; ++i) sum += base[(size_t)i * (H_ * D_)];
  __shared__ float red[4][64];
  red[w][lane] = sum;
  __syncthreads();
  if (w == 0)
    ws[(size_t)g * 64 + lane] =
        red[0][lane] + red[1][lane] + red[2][lane] + red[3][lane];
}

// ---- stage 2: 32 blocks x 64 threads, combine 16 partials, write mean(V) row.
__global__ __launch_bounds__(64) void vmean_comb(const float* __restrict__ ws,
                                                 float* __restrict__ Og) {
  const int bh = blockIdx.x;
  const int b = bh >> 4, h = bh & 15;
  const int lane = (int)threadIdx.x;
  float t = 0.f;
#pragma unroll
  for (int i = 0; i < 16; ++i) t += ws[(size_t)(bh * 16 + i) * 64 + lane];
  Og[((size_t)((b * L_ + (L_ - 1)) * H_ + h)) * D_ + lane] = t * (1.0f / (float)S_);
}

// Fallback (old slow path) in case ws is too small — deterministic per-harness.
__global__ __launch_bounds__(256) void vmean_fix(const float* __restrict__ Vg,
                                                 float* __restrict__ Og) {
  const int bh = blockIdx.x;
  const int b = bh >> 4, h = bh & 15;
  const int t = (int)threadIdx.x;
  const int lane = t & 63, w = t >> 6;
  float sum = 0.f;
  for (int s = w; s < S_; s += 4)
    sum += Vg[((size_t)((b * S_ + s) * H_ + h)) * D_ + lane];
  __shared__ float red[4][64];
  red[w][lane] = sum;
  __syncthreads();
  if (w == 0) {
    float tot = red[0][lane] + red[1][lane] + red[2][lane] + red[3][lane];
    Og[((size_t)((b * L_ + (L_ - 1)) * H_ + h)) * D_ + lane] = tot * (1.0f / (float)S_);
  }
}

extern "C" void kernel_launch(void* const* d_in, const int* in_sizes, int n_in,
                              void* d_out, int out_size, void* d_ws, size_t ws_size,
                              hipStream_t stream) {
  const float* Q = (const float*)d_in[0];
  const float* K = (const float*)d_in[1];
  const float* V = (const float*)d_in[2];
  float* O = (float*)d_out;
  dim3 grid(B_ * H_, L_ / 64);   // x = (b,h), y = q-tile
  attn_fwd<<<grid, dim3(256), 0, stream>>>(Q, K, V, O);
  const size_t ws_need = (size_t)(B_ * H_ * 16) * 64 * sizeof(float);
  if (ws_size >= ws_need) {
    float* ws = (float*)d_ws;
    vmean_part<<<dim3(B_ * H_ * 16), dim3(256), 0, stream>>>(V, ws);
    vmean_comb<<<dim3(B_ * H_), dim3(64), 0, stream>>>(ws, O);
  } else {
    vmean_fix<<<dim3(B_ * H_), dim3(256), 0, stream>>>(V, O);
  }
}